// Round 1
// baseline (452.051 us; speedup 1.0000x reference)
//
#include <hip/hip_runtime.h>
#include <hip/hip_bf16.h>
#include <stdint.h>

// Problem constants (fixed by setup_inputs)
#define NTOK   8192
#define TOPK   2
#define NEXP   8
#define DIN    2048
#define DOUT   2048
#define NK     (NTOK*TOPK)

// GEMM tiling: 256(M) x 256(N) tile, BK=32, 8 waves as 2(M) x 4(N),
// wave tile 128x64 = 8x4 MFMA 16x16x32 bf16 frags.
#define BM 256
#define BN 256
#define BK 32
#define KTILES   (DIN/BK)          // 64
#define ABYTES   (BM*BK*2)         // 16 KB per K-tile of A
#define BBYTES   (BN*BK*2)         // 16 KB per K-tile of B
#define BUFBYTES (ABYTES+BBYTES)   // 32 KB
#define NBUF 3                     // 96 KB LDS ring, prefetch depth 2 tiles

typedef __bf16 bf16_8 __attribute__((ext_vector_type(8)));  // 4 VGPRs, MFMA A/B frag
typedef float  f32x4  __attribute__((ext_vector_type(4)));  // MFMA C/D frag

// global->LDS direct load, 16B per lane. LDS dest = wave-uniform base + lane*16.
__device__ __forceinline__ void gl2lds16(const void* g, void* l) {
  auto gp = reinterpret_cast<const __attribute__((address_space(1))) uint32_t*>(
      reinterpret_cast<uintptr_t>(g));
  auto lp = reinterpret_cast<__attribute__((address_space(3))) uint32_t*>(
      reinterpret_cast<uintptr_t>(l));
  __builtin_amdgcn_global_load_lds(gp, lp, 16, 0, 0);
}

// Fused fp32 -> bf16 (RNE) for W then X. 8 elems/thread, 16B stores.
__global__ void cvt_all(const float4* __restrict__ w, uint4* __restrict__ wD,
                        const float4* __restrict__ x, uint4* __restrict__ xD,
                        int nW) {
  int b = blockIdx.x;
  const float4* src;
  uint4* dst;
  int i;
  if (b < nW) { src = w; dst = wD; i = b * 256 + threadIdx.x; }
  else        { src = x; dst = xD; i = (b - nW) * 256 + threadIdx.x; }
  float4 a0 = src[2 * i];
  float4 a1 = src[2 * i + 1];
  union { __bf16 h[8]; uint4 u; } r;
  r.h[0] = (__bf16)a0.x; r.h[1] = (__bf16)a0.y; r.h[2] = (__bf16)a0.z; r.h[3] = (__bf16)a0.w;
  r.h[4] = (__bf16)a1.x; r.h[5] = (__bf16)a1.y; r.h[6] = (__bf16)a1.z; r.h[7] = (__bf16)a1.w;
  dst[i] = r.u;
}

// Grouped GEMM over expert-sorted flat rows — counted-vmcnt phase pipeline.
//
// Schedule (per K-tile t, 2 phases, 16 MFMA each):
//  ph1: ds_read af[0..3]+bf[0..3] of tile t; issue stage(t+2) (4 gload_lds);
//       s_barrier; MFMA am0-3 x bn0-3 (setprio 1); s_barrier.
//  ph2: ds_read ag[0..3] (rows +64); s_waitcnt vmcnt(4)  [= tile t+1 arrived,
//       only stage(t+2)'s 4 loads left in flight]; s_barrier (joint arrival);
//       MFMA am4-7 x bn0-3; s_barrier.
// Invariants:
//  - stage(t+2) targets buf[(t-1)%3]; all reads of tile t-1 were consumed by
//    MFMAs before t-1.ph2's closing barrier -> WAR safe.
//  - vmcnt never drains to 0 until the 2-tile tail; each tile's loads get
//    3 phases of MFMA cover.
//  - no __syncthreads in the loop (raw s_barrier; no compiler vmcnt(0) drain).
//
// LDS bank-conflict swizzle (unchanged, measured 0 conflicts): row r's 16B
// chunk q lives at chunk slot q ^ s(r), s(r) = (r>>1)&3. Staging lane loads
// global chunk (tid&3)^((tid>>3)&3); reader xors kq by (lr>>1)&3. s(r) is
// invariant under r += multiples of 8 -> one formula serves all waves/frags.
__global__ __launch_bounds__(512, 2)
void moe_gemm(const __bf16* __restrict__ X,     // [NTOK, DIN] bf16
              const __bf16* __restrict__ W,     // [NEXP, DOUT, DIN] bf16 (B^T form)
              const int* __restrict__ ssi,      // sorted_scattered_idxs [NK]
              const int* __restrict__ offs,     // expert_offsets [NEXP]
              __bf16* __restrict__ flat)        // [NK, DOUT] bf16 out (ungated)
{
  __shared__ char lds[NBUF * BUFBYTES];   // 96 KB ring
  __shared__ int  sTok[BM];
  __shared__ int  sF[BM];

  const int tid = threadIdx.x;
  const int bid = blockIdx.x;
  const int nt  = bid & 7;          // 8 N-tiles of 256
  const int mtg = bid >> 3;         // linear M-tile over all experts

  // Map linear M-tile -> (expert e, tile-in-segment). Uniform scan of 8 offsets.
  int start = 0, end = 0, e, cum = 0, prev = 0, mloc = 0, found = 0;
  for (e = 0; e < NEXP; ++e) {
    int oe  = offs[e];
    int seg = oe - prev;
    int t   = (seg + BM - 1) >> 8;
    if (mtg < cum + t) { start = prev; end = oe; mloc = mtg - cum; found = 1; break; }
    cum += t; prev = oe;
  }
  if (!found) return;  // pad block (uniform exit)

  const int m0 = start + mloc * BM;

  if (tid < BM) {
    int p     = m0 + tid;
    int valid = p < end;
    int f     = ssi[valid ? p : (end - 1)];  // clamp keeps gather in-bounds
    sTok[tid] = f >> 1;                      // token = flat / k (k=2)
    sF[tid]   = valid ? f : -1;
  }
  __syncthreads();   // drains all counters -> clean slate for counted regime

  // Staging: thread tid owns row rs = tid>>2 (lo half) and rs+128 (hi half),
  // swizzled k-chunk kc. LDS dest linear: wave slice base + lane*16.
  const int rs = tid >> 2;                       // 0..127
  const int kc = (tid & 3) ^ ((tid >> 3) & 3);   // swizzled chunk
  const __bf16* pA0 = X + (size_t)sTok[rs]       * DIN + kc * 8;
  const __bf16* pA1 = X + (size_t)sTok[rs + 128] * DIN + kc * 8;
  const __bf16* wBp = W + (size_t)e * DOUT * DIN + (size_t)(nt * BN) * DIN;
  const __bf16* pB0 = wBp + (size_t)rs * DIN + kc * 8;
  const __bf16* pB1 = wBp + (size_t)(rs + 128) * DIN + kc * 8;
  char* wsl = (char*)lds + (tid >> 6) * 1024;    // wave-uniform slice base

  // Prologue: stage tiles 0 and 1 into ring slots 0,1.
  gl2lds16(pA0, wsl);           gl2lds16(pA1, wsl + 8192);
  gl2lds16(pB0, wsl + 16384);   gl2lds16(pB1, wsl + 24576);
  pA0 += BK; pA1 += BK; pB0 += BK; pB1 += BK;
  gl2lds16(pA0, wsl + BUFBYTES);          gl2lds16(pA1, wsl + BUFBYTES + 8192);
  gl2lds16(pB0, wsl + BUFBYTES + 16384);  gl2lds16(pB1, wsl + BUFBYTES + 24576);
  pA0 += BK; pA1 += BK; pB0 += BK; pB1 += BK;   // now at tile-2 source offset

  // Fragment addressing. A frag: lane holds A[m=lr][k=kq*8+j]; LDS row = 64 B.
  const int w   = tid >> 6;
  const int l   = tid & 63;
  const int wm  = w >> 2, wn = w & 3;            // 2 x 4 wave grid
  const int lr  = l & 15;
  const int kq  = l >> 4;
  const int kqs = kq ^ ((lr >> 1) & 3);          // bank-conflict swizzle
  const char* aBase = (const char*)lds + (wm * 128 + lr) * 64 + kqs * 16;
  const char* bBase = (const char*)lds + ABYTES + (wn * 64 + lr) * 64 + kqs * 16;

  // Tile 0 arrival (own loads), then joint barrier.
  asm volatile("s_waitcnt vmcnt(4)" ::: "memory");
  __builtin_amdgcn_s_barrier();

  f32x4 acc[8][4] = {};
  int rOff = 0;                    // read slot byte offset (t % 3)
  int sOff = 2 * BUFBYTES;         // stage slot byte offset ((t+2) % 3)

  for (int t = 0; t < KTILES; ++t) {
    const char* aB = aBase + rOff;
    const char* bB = bBase + rOff;

    // ---- phase 1 ----
    bf16_8 af[4], bf[4];
#pragma unroll
    for (int i = 0; i < 4; ++i) af[i] = *(const bf16_8*)(aB + i * 1024);  // rows i*16
#pragma unroll
    for (int i = 0; i < 4; ++i) bf[i] = *(const bf16_8*)(bB + i * 1024);  // cols i*16
    if (t < KTILES - 2) {
      char* d = wsl + sOff;
      gl2lds16(pA0, d);           gl2lds16(pA1, d + 8192);
      gl2lds16(pB0, d + 16384);   gl2lds16(pB1, d + 24576);
      pA0 += BK; pA1 += BK; pB0 += BK; pB1 += BK;
    }
    __builtin_amdgcn_s_barrier();
    __builtin_amdgcn_s_setprio(1);
#pragma unroll
    for (int am = 0; am < 4; ++am)
#pragma unroll
      for (int bn = 0; bn < 4; ++bn)
        acc[am][bn] = __builtin_amdgcn_mfma_f32_16x16x32_bf16(
            af[am], bf[bn], acc[am][bn], 0, 0, 0);
    __builtin_amdgcn_s_setprio(0);
    __builtin_amdgcn_s_barrier();

    // ---- phase 2 ----
    bf16_8 ag[4];
#pragma unroll
    for (int i = 0; i < 4; ++i) ag[i] = *(const bf16_8*)(aB + 4096 + i * 1024); // rows 64+i*16
    if (t < KTILES - 2)       { asm volatile("s_waitcnt vmcnt(4)" ::: "memory"); }
    else if (t == KTILES - 2) { asm volatile("s_waitcnt vmcnt(0)" ::: "memory"); }
    __builtin_amdgcn_s_barrier();   // joint: tile t+1 fully resident for all waves
    __builtin_amdgcn_s_setprio(1);
#pragma unroll
    for (int am = 0; am < 4; ++am)
#pragma unroll
      for (int bn = 0; bn < 4; ++bn)
        acc[am + 4][bn] = __builtin_amdgcn_mfma_f32_16x16x32_bf16(
            ag[am], bf[bn], acc[am + 4][bn], 0, 0, 0);
    __builtin_amdgcn_s_setprio(0);
    __builtin_amdgcn_s_barrier();

    rOff = (rOff == (NBUF - 1) * BUFBYTES) ? 0 : rOff + BUFBYTES;
    sOff = (sOff == (NBUF - 1) * BUFBYTES) ? 0 : sOff + BUFBYTES;
  }

  // Epilogue: C/D layout col=lane&15, row=(lane>>4)*4+reg.
  const int colBase = nt * BN + wn * 64 + lr;
  const int rq = kq * 4;
#pragma unroll
  for (int am = 0; am < 8; ++am) {
#pragma unroll
    for (int v = 0; v < 4; ++v) {
      int rl = wm * 128 + am * 16 + rq + v;
      int f  = sF[rl];
      if (f < 0) continue;
      __bf16* row = flat + (size_t)f * DOUT + colBase;
#pragma unroll
      for (int bn = 0; bn < 4; ++bn)
        row[bn * 16] = (__bf16)acc[am][bn][v];
    }
  }
}

// out[n, :] = g[2n]*flat[2n, :] + g[2n+1]*flat[2n+1, :]
__global__ __launch_bounds__(256)
void combine(const __bf16* __restrict__ flat, const float* __restrict__ gates,
             float* __restrict__ out) {
  const int n = blockIdx.x;
  const int c = threadIdx.x * 8;
  bf16_8 y0 = *(const bf16_8*)(flat + (size_t)(2 * n)     * DOUT + c);
  bf16_8 y1 = *(const bf16_8*)(flat + (size_t)(2 * n + 1) * DOUT + c);
  const float2 g = *(const float2*)(gates + 2 * n);
  float o[8];
#pragma unroll
  for (int j = 0; j < 8; ++j)
    o[j] = g.x * (float)y0[j] + g.y * (float)y1[j];
  float4* dst = (float4*)(out + (size_t)n * DOUT + c);
  dst[0] = *(float4*)&o[0];
  dst[1] = *(float4*)&o[4];
}

extern "C" void kernel_launch(void* const* d_in, const int* in_sizes, int n_in,
                              void* d_out, int out_size, void* d_ws, size_t ws_size,
                              hipStream_t stream) {
  const float* inputs = (const float*)d_in[0];   // [8192, 2048]
  const float* ew     = (const float*)d_in[1];   // [8, 2048, 2048] (E, out, in)
  const float* gates  = (const float*)d_in[2];   // [8192, 2]
  const int*   ssi    = (const int*)d_in[5];     // sorted_scattered_idxs [16384]
  const int*   offs   = (const int*)d_in[6];     // expert_offsets [8]
  float* out = (float*)d_out;

  // ws layout: bf16 W (64 MB) | bf16 X (32 MB) | bf16 flat out (64 MB)
  __bf16* wsW = (__bf16*)d_ws;
  __bf16* wsX = wsW + (size_t)NEXP * DOUT * DIN;
  __bf16* wsF = wsX + (size_t)NTOK * DIN;

  const int n8w = NEXP * DOUT * DIN / 8;   // 4194304 -> 16384 blocks
  const int n8x = NTOK * DIN / 8;          // 2097152 ->  8192 blocks
  const int nWb = n8w / 256, nXb = n8x / 256;
  cvt_all<<<nWb + nXb, 256, 0, stream>>>((const float4*)ew, (uint4*)wsW,
                                         (const float4*)inputs, (uint4*)wsX, nWb);

  // max M-tiles = 64 + 8 (per-expert ceil padding), 8 N-tiles of 256
  moe_gemm<<<72 * 8, 512, 0, stream>>>(wsX, wsW, ssi, offs, wsF);
  combine<<<NTOK, 256, 0, stream>>>(wsF, gates, out);
}

// Round 2
// 448.573 us; speedup vs baseline: 1.0078x; 1.0078x over previous
//
#include <hip/hip_runtime.h>
#include <hip/hip_bf16.h>
#include <stdint.h>

// Problem constants (fixed by setup_inputs)
#define NTOK   8192
#define TOPK   2
#define NEXP   8
#define DIN    2048
#define DOUT   2048
#define NK     (NTOK*TOPK)

// GEMM tiling: 256(M) x 256(N) tile, BK=32, 8 waves as 2(M) x 4(N),
// wave tile 128x64 = 8x4 MFMA 16x16x32 bf16 frags.
#define BM 256
#define BN 256
#define BK 32
#define KTILES   (DIN/BK)          // 64
#define ABYTES   (BM*BK*2)         // 16 KB per K-tile of A
#define BBYTES   (BN*BK*2)         // 16 KB per K-tile of B
#define BUFBYTES (ABYTES+BBYTES)   // 32 KB
#define NBUF 4                     // 128 KB LDS ring, prefetch depth 3 tiles

typedef __bf16 bf16_8 __attribute__((ext_vector_type(8)));  // 4 VGPRs, MFMA A/B frag
typedef float  f32x4  __attribute__((ext_vector_type(4)));  // MFMA C/D frag

// global->LDS direct load, 16B per lane. LDS dest = wave-uniform base + lane*16.
__device__ __forceinline__ void gl2lds16(const void* g, void* l) {
  auto gp = reinterpret_cast<const __attribute__((address_space(1))) uint32_t*>(
      reinterpret_cast<uintptr_t>(g));
  auto lp = reinterpret_cast<__attribute__((address_space(3))) uint32_t*>(
      reinterpret_cast<uintptr_t>(l));
  __builtin_amdgcn_global_load_lds(gp, lp, 16, 0, 0);
}

// Fused fp32 -> bf16 (RNE) for W then X. 8 elems/thread, 16B stores.
__global__ void cvt_all(const float4* __restrict__ w, uint4* __restrict__ wD,
                        const float4* __restrict__ x, uint4* __restrict__ xD,
                        int nW) {
  int b = blockIdx.x;
  const float4* src;
  uint4* dst;
  int i;
  if (b < nW) { src = w; dst = wD; i = b * 256 + threadIdx.x; }
  else        { src = x; dst = xD; i = (b - nW) * 256 + threadIdx.x; }
  float4 a0 = src[2 * i];
  float4 a1 = src[2 * i + 1];
  union { __bf16 h[8]; uint4 u; } r;
  r.h[0] = (__bf16)a0.x; r.h[1] = (__bf16)a0.y; r.h[2] = (__bf16)a0.z; r.h[3] = (__bf16)a0.w;
  r.h[4] = (__bf16)a1.x; r.h[5] = (__bf16)a1.y; r.h[6] = (__bf16)a1.z; r.h[7] = (__bf16)a1.w;
  dst[i] = r.u;
}

// Grouped GEMM over expert-sorted flat rows — deep-ring counted-vmcnt pipeline.
//
// Per K-tile t (single phase, 32 MFMA, ONE barrier, ONE counted wait):
//   stage(t+3) -> buf[(t+3)&3]     (4 gload_lds; WAR-safe: buf[(t-1)&3] reads
//                                   all completed before tile t-1's barrier,
//                                   and this issue is after that barrier)
//   ds_read af[0..3], bf[0..3], ag[0..3] of tile t  (compiler counts lgkmcnt)
//   setprio(1); 32 x MFMA; setprio(0)
//   s_waitcnt vmcnt(8)             (tile t+1 landed; t+2,t+3 stay in flight;
//                                   cover for t+1 = ~2 full tiles of MFMA)
//   s_barrier                      (publishes all waves' loads + read-done)
// Tail: vmcnt(4) at t=KTILES-3, vmcnt(0) at t=KTILES-2, nothing at last tile.
// No __syncthreads in the loop -> no compiler-forced vmcnt(0) drain.
//
// LDS bank-conflict swizzle (measured 0 conflicts): row r's 16B chunk q lives
// at chunk slot q ^ s(r), s(r) = (r>>1)&3. Staging lane loads global chunk
// (tid&3)^((tid>>3)&3); reader xors kq by (lr>>1)&3. s(r) is invariant under
// r += multiples of 8 -> one formula serves all waves/frags/halves.
__global__ __launch_bounds__(512, 2)
void moe_gemm(const __bf16* __restrict__ X,     // [NTOK, DIN] bf16
              const __bf16* __restrict__ W,     // [NEXP, DOUT, DIN] bf16 (B^T form)
              const int* __restrict__ ssi,      // sorted_scattered_idxs [NK]
              const int* __restrict__ offs,     // expert_offsets [NEXP]
              __bf16* __restrict__ flat)        // [NK, DOUT] bf16 out (ungated)
{
  __shared__ char lds[NBUF * BUFBYTES];   // 128 KB ring
  __shared__ int  sTok[BM];
  __shared__ int  sF[BM];

  const int tid = threadIdx.x;
  const int bid = blockIdx.x;
  const int nt  = bid & 7;          // 8 N-tiles of 256
  const int mtg = bid >> 3;         // linear M-tile over all experts

  // Map linear M-tile -> (expert e, tile-in-segment). Uniform scan of 8 offsets.
  int start = 0, end = 0, e, cum = 0, prev = 0, mloc = 0, found = 0;
  for (e = 0; e < NEXP; ++e) {
    int oe  = offs[e];
    int seg = oe - prev;
    int t   = (seg + BM - 1) >> 8;
    if (mtg < cum + t) { start = prev; end = oe; mloc = mtg - cum; found = 1; break; }
    cum += t; prev = oe;
  }
  if (!found) return;  // pad block (uniform exit)

  const int m0 = start + mloc * BM;

  if (tid < BM) {
    int p     = m0 + tid;
    int valid = p < end;
    int f     = ssi[valid ? p : (end - 1)];  // clamp keeps gather in-bounds
    sTok[tid] = f >> 1;                      // token = flat / k (k=2)
    sF[tid]   = valid ? f : -1;
  }
  __syncthreads();   // tables visible; clean counter slate before counted regime

  // Staging: thread tid owns row rs = tid>>2 (lo half) and rs+128 (hi half),
  // swizzled k-chunk kc. LDS dest linear: wave slice base + lane*16.
  const int rs = tid >> 2;                       // 0..127
  const int kc = (tid & 3) ^ ((tid >> 3) & 3);   // swizzled chunk
  const __bf16* pA0 = X + (size_t)sTok[rs]       * DIN + kc * 8;
  const __bf16* pA1 = X + (size_t)sTok[rs + 128] * DIN + kc * 8;
  const __bf16* wBp = W + (size_t)e * DOUT * DIN + (size_t)(nt * BN) * DIN;
  const __bf16* pB0 = wBp + (size_t)rs * DIN + kc * 8;
  const __bf16* pB1 = wBp + (size_t)(rs + 128) * DIN + kc * 8;
  char* wsl = (char*)lds + (tid >> 6) * 1024;    // wave-uniform slice base

  // Prologue: stage tiles 0,1,2 into ring slots 0,1,2 (12 loads in flight).
#pragma unroll
  for (int pt = 0; pt < 3; ++pt) {
    char* d = wsl + pt * BUFBYTES;
    gl2lds16(pA0, d);           gl2lds16(pA1, d + 8192);
    gl2lds16(pB0, d + 16384);   gl2lds16(pB1, d + 24576);
    pA0 += BK; pA1 += BK; pB0 += BK; pB1 += BK;
  }

  // Fragment addressing. A frag: lane holds A[m=lr][k=kq*8+j]; LDS row = 64 B.
  const int w   = tid >> 6;
  const int l   = tid & 63;
  const int wm  = w >> 2, wn = w & 3;            // 2 x 4 wave grid
  const int lr  = l & 15;
  const int kq  = l >> 4;
  const int kqs = kq ^ ((lr >> 1) & 3);          // bank-conflict swizzle
  const char* aBase = (const char*)lds + (wm * 128 + lr) * 64 + kqs * 16;
  const char* bBase = (const char*)lds + ABYTES + (wn * 64 + lr) * 64 + kqs * 16;

  // Tile 0 arrival: own 4 oldest loads done (tiles 1,2 may stay in flight).
  asm volatile("s_waitcnt vmcnt(8)" ::: "memory");
  __builtin_amdgcn_s_barrier();

  f32x4 acc[8][4] = {};
  int rOff = 0;                    // read slot byte offset (t & 3)
  int sOff = 3 * BUFBYTES;         // stage slot byte offset ((t+3) & 3)

  for (int t = 0; t < KTILES; ++t) {
    // Issue next prefetch first (VMEM issue is cheap; maximizes cover).
    if (t < KTILES - 3) {
      char* d = wsl + sOff;
      gl2lds16(pA0, d);           gl2lds16(pA1, d + 8192);
      gl2lds16(pB0, d + 16384);   gl2lds16(pB1, d + 24576);
      pA0 += BK; pA1 += BK; pB0 += BK; pB1 += BK;
    }

    const char* aB = aBase + rOff;
    const char* bB = bBase + rOff;
    bf16_8 af[4], bf[4], ag[4];
#pragma unroll
    for (int i = 0; i < 4; ++i) af[i] = *(const bf16_8*)(aB + i * 1024);        // rows i*16
#pragma unroll
    for (int i = 0; i < 4; ++i) bf[i] = *(const bf16_8*)(bB + i * 1024);        // cols i*16
#pragma unroll
    for (int i = 0; i < 4; ++i) ag[i] = *(const bf16_8*)(aB + 4096 + i * 1024); // rows 64+i*16

    __builtin_amdgcn_s_setprio(1);
#pragma unroll
    for (int am = 0; am < 4; ++am)
#pragma unroll
      for (int bn = 0; bn < 4; ++bn)
        acc[am][bn] = __builtin_amdgcn_mfma_f32_16x16x32_bf16(
            af[am], bf[bn], acc[am][bn], 0, 0, 0);
#pragma unroll
    for (int am = 0; am < 4; ++am)
#pragma unroll
      for (int bn = 0; bn < 4; ++bn)
        acc[am + 4][bn] = __builtin_amdgcn_mfma_f32_16x16x32_bf16(
            ag[am], bf[bn], acc[am + 4][bn], 0, 0, 0);
    __builtin_amdgcn_s_setprio(0);

    // Arrival of tile t+1 for next iteration; never drain until the tail.
    if (t < KTILES - 3)       { asm volatile("s_waitcnt vmcnt(8)" ::: "memory"); }
    else if (t == KTILES - 3) { asm volatile("s_waitcnt vmcnt(4)" ::: "memory"); }
    else if (t == KTILES - 2) { asm volatile("s_waitcnt vmcnt(0)" ::: "memory"); }
    if (t < KTILES - 1) __builtin_amdgcn_s_barrier();

    rOff = (rOff + BUFBYTES) & (NBUF * BUFBYTES - 1);
    sOff = (sOff + BUFBYTES) & (NBUF * BUFBYTES - 1);
  }

  // Epilogue: C/D layout col=lane&15, row=(lane>>4)*4+reg.
  const int colBase = nt * BN + wn * 64 + lr;
  const int rq = kq * 4;
#pragma unroll
  for (int am = 0; am < 8; ++am) {
#pragma unroll
    for (int v = 0; v < 4; ++v) {
      int rl = wm * 128 + am * 16 + rq + v;
      int f  = sF[rl];
      if (f < 0) continue;
      __bf16* row = flat + (size_t)f * DOUT + colBase;
#pragma unroll
      for (int bn = 0; bn < 4; ++bn)
        row[bn * 16] = (__bf16)acc[am][bn][v];
    }
  }
}

// out[n, :] = g[2n]*flat[2n, :] + g[2n+1]*flat[2n+1, :]
__global__ __launch_bounds__(256)
void combine(const __bf16* __restrict__ flat, const float* __restrict__ gates,
             float* __restrict__ out) {
  const int n = blockIdx.x;
  const int c = threadIdx.x * 8;
  bf16_8 y0 = *(const bf16_8*)(flat + (size_t)(2 * n)     * DOUT + c);
  bf16_8 y1 = *(const bf16_8*)(flat + (size_t)(2 * n + 1) * DOUT + c);
  const float2 g = *(const float2*)(gates + 2 * n);
  float o[8];
#pragma unroll
  for (int j = 0; j < 8; ++j)
    o[j] = g.x * (float)y0[j] + g.y * (float)y1[j];
  float4* dst = (float4*)(out + (size_t)n * DOUT + c);
  dst[0] = *(float4*)&o[0];
  dst[1] = *(float4*)&o[4];
}

extern "C" void kernel_launch(void* const* d_in, const int* in_sizes, int n_in,
                              void* d_out, int out_size, void* d_ws, size_t ws_size,
                              hipStream_t stream) {
  const float* inputs = (const float*)d_in[0];   // [8192, 2048]
  const float* ew     = (const float*)d_in[1];   // [8, 2048, 2048] (E, out, in)
  const float* gates  = (const float*)d_in[2];   // [8192, 2]
  const int*   ssi    = (const int*)d_in[5];     // sorted_scattered_idxs [16384]
  const int*   offs   = (const int*)d_in[6];     // expert_offsets [8]
  float* out = (float*)d_out;

  // ws layout: bf16 W (64 MB) | bf16 X (32 MB) | bf16 flat out (64 MB)
  __bf16* wsW = (__bf16*)d_ws;
  __bf16* wsX = wsW + (size_t)NEXP * DOUT * DIN;
  __bf16* wsF = wsX + (size_t)NTOK * DIN;

  const int n8w = NEXP * DOUT * DIN / 8;   // 4194304 -> 16384 blocks
  const int n8x = NTOK * DIN / 8;          // 2097152 ->  8192 blocks
  const int nWb = n8w / 256, nXb = n8x / 256;
  cvt_all<<<nWb + nXb, 256, 0, stream>>>((const float4*)ew, (uint4*)wsW,
                                         (const float4*)inputs, (uint4*)wsX, nWb);

  // max M-tiles = 64 + 8 (per-expert ceil padding), 8 N-tiles of 256
  moe_gemm<<<72 * 8, 512, 0, stream>>>(wsX, wsW, ssi, offs, wsF);
  combine<<<NTOK, 256, 0, stream>>>(wsF, gates, out);
}

// Round 3
// 437.001 us; speedup vs baseline: 1.0344x; 1.0265x over previous
//
#include <hip/hip_runtime.h>
#include <hip/hip_bf16.h>
#include <stdint.h>

// Problem constants (fixed by setup_inputs)
#define NTOK   8192
#define TOPK   2
#define NEXP   8
#define DIN    2048
#define DOUT   2048
#define NK     (NTOK*TOPK)

// GEMM tiling: 256(M) x 128(N) tile (R0 geometry), BK=32, 8 waves as 4(M) x 2(N),
// wave tile 64x64 = 4x4 MFMA 16x16x32 bf16 frags.
#define BM 256
#define BN 128
#define BK 32
#define KTILES  (DIN/BK)           // 64
#define SLOT    24576              // per-K-tile LDS: A 16 KB + B 8 KB
#define NBUF    3                  // 72 KB ring, prefetch depth 2 tiles

typedef __bf16 bf16_8 __attribute__((ext_vector_type(8)));  // 4 VGPRs, MFMA A/B frag
typedef float  f32x4  __attribute__((ext_vector_type(4)));  // MFMA C/D frag

// global->LDS direct load, 16B per lane. LDS dest = wave-uniform base + lane*16.
__device__ __forceinline__ void gl2lds16(const void* g, void* l) {
  auto gp = reinterpret_cast<const __attribute__((address_space(1))) uint32_t*>(
      reinterpret_cast<uintptr_t>(g));
  auto lp = reinterpret_cast<__attribute__((address_space(3))) uint32_t*>(
      reinterpret_cast<uintptr_t>(l));
  __builtin_amdgcn_global_load_lds(gp, lp, 16, 0, 0);
}

// Fused fp32 -> bf16 (RNE) for W then X. 8 elems/thread, 16B stores.
__global__ void cvt_all(const float4* __restrict__ w, uint4* __restrict__ wD,
                        const float4* __restrict__ x, uint4* __restrict__ xD,
                        int nW) {
  int b = blockIdx.x;
  const float4* src;
  uint4* dst;
  int i;
  if (b < nW) { src = w; dst = wD; i = b * 256 + threadIdx.x; }
  else        { src = x; dst = xD; i = (b - nW) * 256 + threadIdx.x; }
  float4 a0 = src[2 * i];
  float4 a1 = src[2 * i + 1];
  union { __bf16 h[8]; uint4 u; } r;
  r.h[0] = (__bf16)a0.x; r.h[1] = (__bf16)a0.y; r.h[2] = (__bf16)a0.z; r.h[3] = (__bf16)a0.w;
  r.h[4] = (__bf16)a1.x; r.h[5] = (__bf16)a1.y; r.h[6] = (__bf16)a1.z; r.h[7] = (__bf16)a1.w;
  dst[i] = r.u;
}

// Grouped GEMM over expert-sorted flat rows.
// R0 geometry (256x128, proven 174 us / 37% MfmaUtil) + counted-vmcnt ring
// (proven correct in R2): NBUF=3, depth-2 prefetch, ONE raw s_barrier and ONE
// counted vmcnt(3) per K-tile — no __syncthreads drain in the loop.
//
// Per K-tile t:
//   stage(t+2) -> slot (t+2)%3   (3 gload_lds; WAR-safe: slot (t-1)%3's reads
//                                 were consumed by MFMAs before the end-of-(t-1)
//                                 barrier, and this issue is after it)
//   ds_read af[0..3], bf[0..3] of tile t (compiler-counted lgkmcnt)
//   16 x MFMA
//   s_waitcnt vmcnt(3)           (tile t+1 landed; t+2's 3 loads stay in
//                                 flight; cover for t+1 = ~2 tiles of work)
//   s_barrier
// Tail: vmcnt(0) at t=KTILES-2 (drains last tile), no sync after last tile.
//
// LDS bank-conflict swizzle (measured 0 conflicts): row r's 16B chunk q lives
// at chunk slot q ^ s(r), s(r) = (r>>1)&3. Staging lane loads global chunk
// (tid&3)^((tid>>3)&3); reader xors kq by (lr>>1)&3. s(r) invariant under
// r += multiples of 8 -> one formula serves all waves/frags.
//
// LDS total ~74 KB -> 2 blocks/CU: cross-block TLP absorbs barrier/LDS gaps
// (the lesson of R1/R2: 1-block/CU lockstep cannot).
__global__ __launch_bounds__(512, 4)
void moe_gemm(const __bf16* __restrict__ X,     // [NTOK, DIN] bf16
              const __bf16* __restrict__ W,     // [NEXP, DOUT, DIN] bf16 (B^T form)
              const int* __restrict__ ssi,      // sorted_scattered_idxs [NK]
              const int* __restrict__ offs,     // expert_offsets [NEXP]
              __bf16* __restrict__ flat)        // [NK, DOUT] bf16 out (ungated)
{
  __shared__ char lds[NBUF * SLOT];   // 72 KB ring: per slot A 16 KB | B 8 KB
  __shared__ int  sTok[BM];
  __shared__ int  sF[BM];

  const int tid = threadIdx.x;
  const int bid = blockIdx.x;
  const int nt  = bid & 15;         // 16 N-tiles of 128
  const int mtg = bid >> 4;         // linear M-tile over all experts

  // Map linear M-tile -> (expert e, tile-in-segment). Uniform scan of 8 offsets.
  int start = 0, end = 0, e, cum = 0, prev = 0, mloc = 0, found = 0;
  for (e = 0; e < NEXP; ++e) {
    int oe  = offs[e];
    int seg = oe - prev;
    int t   = (seg + BM - 1) >> 8;
    if (mtg < cum + t) { start = prev; end = oe; mloc = mtg - cum; found = 1; break; }
    cum += t; prev = oe;
  }
  if (!found) return;  // pad block (uniform exit)

  const int m0 = start + mloc * BM;

  if (tid < BM) {
    int p     = m0 + tid;
    int valid = p < end;
    int f     = ssi[valid ? p : (end - 1)];  // clamp keeps gather in-bounds
    sTok[tid] = f >> 1;                      // token = flat / k (k=2)
    sF[tid]   = valid ? f : -1;
  }
  __syncthreads();   // tables visible; full drain -> clean slate for counted regime

  // Staging: thread tid owns A rows rs = tid>>2 and rs+128, B row rs,
  // swizzled k-chunk kc. LDS dest linear: wave slice base + lane*16.
  const int rs = tid >> 2;                       // 0..127
  const int kc = (tid & 3) ^ ((tid >> 3) & 3);   // swizzled chunk
  const __bf16* pA0 = X + (size_t)sTok[rs]       * DIN + kc * 8;
  const __bf16* pA1 = X + (size_t)sTok[rs + 128] * DIN + kc * 8;
  const __bf16* wBp = W + (size_t)e * DOUT * DIN + (size_t)(nt * BN) * DIN;
  const __bf16* pB0 = wBp + (size_t)rs * DIN + kc * 8;
  char* wsl = (char*)lds + (tid >> 6) * 1024;    // wave-uniform slice base

  // Prologue: stage tiles 0,1 into slots 0,1 (6 loads in flight).
  gl2lds16(pA0, wsl);           gl2lds16(pA1, wsl + 8192);
  gl2lds16(pB0, wsl + 16384);
  pA0 += BK; pA1 += BK; pB0 += BK;
  gl2lds16(pA0, wsl + SLOT);    gl2lds16(pA1, wsl + SLOT + 8192);
  gl2lds16(pB0, wsl + SLOT + 16384);
  pA0 += BK; pA1 += BK; pB0 += BK;   // now at tile-2 source offset

  // Fragment addressing. A frag: lane holds A[m=lr][k=kq*8+j]; LDS row = 64 B.
  const int w   = tid >> 6;
  const int l   = tid & 63;
  const int wm  = w >> 1, wn = w & 1;            // 4 x 2 wave grid
  const int lr  = l & 15;
  const int kq  = l >> 4;
  const int kqs = kq ^ ((lr >> 1) & 3);          // bank-conflict swizzle
  const char* aBase = (const char*)lds + (wm * 64 + lr) * 64 + kqs * 16;
  const char* bBase = (const char*)lds + 16384 + (wn * 64 + lr) * 64 + kqs * 16;

  // Tile 0 arrival: own 3 oldest loads done (tile 1's may stay in flight).
  asm volatile("s_waitcnt vmcnt(3)" ::: "memory");
  __builtin_amdgcn_s_barrier();

  f32x4 acc[4][4] = {};
  int rOff = 0;               // read slot byte offset (t % 3)
  int sOff = 2 * SLOT;        // stage slot byte offset ((t+2) % 3)

  for (int t = 0; t < KTILES; ++t) {
    // Issue next prefetch first (maximizes cover; 3 VMEM issues are cheap).
    if (t < KTILES - 2) {
      char* d = wsl + sOff;
      gl2lds16(pA0, d);  gl2lds16(pA1, d + 8192);  gl2lds16(pB0, d + 16384);
      pA0 += BK; pA1 += BK; pB0 += BK;
      sOff = (sOff == (NBUF - 1) * SLOT) ? 0 : sOff + SLOT;
    }

    const char* aB = aBase + rOff;
    const char* bB = bBase + rOff;
    rOff = (rOff == (NBUF - 1) * SLOT) ? 0 : rOff + SLOT;

    bf16_8 af[4], bf[4];
#pragma unroll
    for (int i = 0; i < 4; ++i) af[i] = *(const bf16_8*)(aB + i * 1024);  // rows i*16
#pragma unroll
    for (int i = 0; i < 4; ++i) bf[i] = *(const bf16_8*)(bB + i * 1024);  // cols i*16

#pragma unroll
    for (int am = 0; am < 4; ++am)
#pragma unroll
      for (int bn = 0; bn < 4; ++bn)
        acc[am][bn] = __builtin_amdgcn_mfma_f32_16x16x32_bf16(
            af[am], bf[bn], acc[am][bn], 0, 0, 0);

    // Arrival of tile t+1 for next iteration; never drain until the tail.
    if (t < KTILES - 2)       { asm volatile("s_waitcnt vmcnt(3)" ::: "memory"); }
    else if (t == KTILES - 2) { asm volatile("s_waitcnt vmcnt(0)" ::: "memory"); }
    if (t < KTILES - 1) __builtin_amdgcn_s_barrier();
  }

  // Epilogue: C/D layout col=lane&15, row=(lane>>4)*4+reg.
  const int colBase = nt * BN + wn * 64 + lr;
  const int rq = kq * 4;
#pragma unroll
  for (int am = 0; am < 4; ++am) {
#pragma unroll
    for (int v = 0; v < 4; ++v) {
      int rl = wm * 64 + am * 16 + rq + v;
      int f  = sF[rl];
      if (f < 0) continue;
      __bf16* row = flat + (size_t)f * DOUT + colBase;
#pragma unroll
      for (int bn = 0; bn < 4; ++bn)
        row[bn * 16] = (__bf16)acc[am][bn][v];
    }
  }
}

// out[n, :] = g[2n]*flat[2n, :] + g[2n+1]*flat[2n+1, :]
__global__ __launch_bounds__(256)
void combine(const __bf16* __restrict__ flat, const float* __restrict__ gates,
             float* __restrict__ out) {
  const int n = blockIdx.x;
  const int c = threadIdx.x * 8;
  bf16_8 y0 = *(const bf16_8*)(flat + (size_t)(2 * n)     * DOUT + c);
  bf16_8 y1 = *(const bf16_8*)(flat + (size_t)(2 * n + 1) * DOUT + c);
  const float2 g = *(const float2*)(gates + 2 * n);
  float o[8];
#pragma unroll
  for (int j = 0; j < 8; ++j)
    o[j] = g.x * (float)y0[j] + g.y * (float)y1[j];
  float4* dst = (float4*)(out + (size_t)n * DOUT + c);
  dst[0] = *(float4*)&o[0];
  dst[1] = *(float4*)&o[4];
}

extern "C" void kernel_launch(void* const* d_in, const int* in_sizes, int n_in,
                              void* d_out, int out_size, void* d_ws, size_t ws_size,
                              hipStream_t stream) {
  const float* inputs = (const float*)d_in[0];   // [8192, 2048]
  const float* ew     = (const float*)d_in[1];   // [8, 2048, 2048] (E, out, in)
  const float* gates  = (const float*)d_in[2];   // [8192, 2]
  const int*   ssi    = (const int*)d_in[5];     // sorted_scattered_idxs [16384]
  const int*   offs   = (const int*)d_in[6];     // expert_offsets [8]
  float* out = (float*)d_out;

  // ws layout: bf16 W (64 MB) | bf16 X (32 MB) | bf16 flat out (64 MB)
  __bf16* wsW = (__bf16*)d_ws;
  __bf16* wsX = wsW + (size_t)NEXP * DOUT * DIN;
  __bf16* wsF = wsX + (size_t)NTOK * DIN;

  const int n8w = NEXP * DOUT * DIN / 8;   // 4194304 -> 16384 blocks
  const int n8x = NTOK * DIN / 8;          // 2097152 ->  8192 blocks
  const int nWb = n8w / 256, nXb = n8x / 256;
  cvt_all<<<nWb + nXb, 256, 0, stream>>>((const float4*)ew, (uint4*)wsW,
                                         (const float4*)inputs, (uint4*)wsX, nWb);

  // max M-tiles = 64 + 8 (per-expert ceil padding), 16 N-tiles of 128
  moe_gemm<<<72 * 16, 512, 0, stream>>>(wsX, wsW, ssi, offs, wsF);
  combine<<<NTOK, 256, 0, stream>>>(wsF, gates, out);
}